// Round 1
// baseline (12215.451 us; speedup 1.0000x reference)
//
#include <hip/hip_runtime.h>
#include <math.h>

// ---- problem constants ----
#define V_   256
#define S_   1024
#define D_   768
#define H_   12
#define L_   4
#define DS_  3
#define B_   4
#define DH_  64        // D_/H_
#define BS_  (B_*S_)   // 4096
#define D3_  (3*D_)    // 2304
#define D4_  (4*D_)    // 3072
#define BSV_ (BS_*V_)  // 1048576

// ---------------------------------------------------------------
// block-wide reductions (256 threads = 4 waves of 64)
// ---------------------------------------------------------------
__device__ __forceinline__ float block_sum(float v, float* red) {
    #pragma unroll
    for (int m = 32; m > 0; m >>= 1) v += __shfl_xor(v, m, 64);
    int wid = threadIdx.x >> 6;
    __syncthreads();                       // protect red[] reuse
    if ((threadIdx.x & 63) == 0) red[wid] = v;
    __syncthreads();
    return red[0] + red[1] + red[2] + red[3];
}

__device__ __forceinline__ float block_max(float v, float* red) {
    #pragma unroll
    for (int m = 32; m > 0; m >>= 1) v = fmaxf(v, __shfl_xor(v, m, 64));
    int wid = threadIdx.x >> 6;
    __syncthreads();
    if ((threadIdx.x & 63) == 0) red[wid] = v;
    __syncthreads();
    return fmaxf(fmaxf(red[0], red[1]), fmaxf(red[2], red[3]));
}

// ---------------------------------------------------------------
// zero the scalar accumulators
// ---------------------------------------------------------------
__global__ void zero_kernel(float* acc) {
    if (threadIdx.x < 8) acc[threadIdx.x] = 0.0f;
}

// ---------------------------------------------------------------
// embedding: x = tok_emb[idx] + pos_emb[t] + sp @ pproj ; stash sp
// one block per (b*S+t)
// ---------------------------------------------------------------
__global__ __launch_bounds__(256) void embed_kernel(
    const int* __restrict__ idx, const float* __restrict__ tok_emb,
    const float* __restrict__ pos_emb, const float* __restrict__ tok_pos,
    const float* __restrict__ pproj, float* __restrict__ x, float* __restrict__ sp)
{
    int r = blockIdx.x;                 // b*S + t
    int t = r & (S_ - 1);
    int id = idx[r];
    float s0 = tok_pos[id*3+0], s1 = tok_pos[id*3+1], s2 = tok_pos[id*3+2];
    if (threadIdx.x == 0) { sp[r*3+0] = s0; sp[r*3+1] = s1; sp[r*3+2] = s2; }
    for (int d = threadIdx.x; d < D_; d += 256) {
        x[(size_t)r*D_ + d] = tok_emb[(size_t)id*D_ + d] + pos_emb[(size_t)t*D_ + d]
                            + s0*pproj[d] + s1*pproj[D_+d] + s2*pproj[2*D_+d];
    }
}

// ---------------------------------------------------------------
// layernorm, one block (256 thr) per row of 768
// ---------------------------------------------------------------
__global__ __launch_bounds__(256) void ln_kernel(
    const float* __restrict__ in, const float* __restrict__ g,
    const float* __restrict__ b, float* __restrict__ out)
{
    __shared__ float red[4];
    int r = blockIdx.x, tid = threadIdx.x;
    const float* p = in + (size_t)r*D_;
    float v0 = p[tid], v1 = p[tid+256], v2 = p[tid+512];
    float s = block_sum(v0+v1+v2, red);
    float mean = s * (1.0f/768.0f);
    float d0 = v0-mean, d1 = v1-mean, d2 = v2-mean;
    float var = block_sum(d0*d0+d1*d1+d2*d2, red) * (1.0f/768.0f);
    float inv = rsqrtf(var + 1e-5f);
    float* o = out + (size_t)r*D_;
    o[tid    ] = d0*inv*g[tid    ] + b[tid    ];
    o[tid+256] = d1*inv*g[tid+256] + b[tid+256];
    o[tid+512] = d2*inv*g[tid+512] + b[tid+512];
}

// ---------------------------------------------------------------
// f32 GEMM  C[M,N] = A[M,K] @ B[K,N]   (BT: B is [N,K], use B^T)
// 64x64 tile, 256 threads, 4x4 per thread, K-tile 16
// EPI: 0=none 1=+res 2=+bias,gelu 3=+bias,+res
// ---------------------------------------------------------------
template<int EPI, bool BT>
__global__ __launch_bounds__(256) void gemm_kernel(
    const float* __restrict__ A, const float* __restrict__ Bm,
    const float* __restrict__ bias, const float* __restrict__ res,
    float* __restrict__ C, int M, int N, int K)
{
    __shared__ float As[16][68];
    __shared__ float Bs[16][68];
    int tid = threadIdx.x;
    int tx = tid & 15, ty = tid >> 4;
    int bn = blockIdx.x * 64, bm = blockIdx.y * 64;
    float acc[4][4] = {};

    int arow = tid >> 2;            // 0..63
    int akc  = (tid & 3) * 4;       // 0,4,8,12
    int kb   = tid >> 4;            // 0..15  (NN B-load row)
    int nb   = (tid & 15) * 4;      // 0..60  (NN B-load col)

    for (int k0 = 0; k0 < K; k0 += 16) {
        float4 av = *(const float4*)&A[(size_t)(bm+arow)*K + k0 + akc];
        As[akc+0][arow] = av.x; As[akc+1][arow] = av.y;
        As[akc+2][arow] = av.z; As[akc+3][arow] = av.w;
        if (!BT) {
            float4 bv = *(const float4*)&Bm[(size_t)(k0+kb)*N + bn + nb];
            *(float4*)&Bs[kb][nb] = bv;
        } else {
            float4 bv = *(const float4*)&Bm[(size_t)(bn+arow)*K + k0 + akc];
            Bs[akc+0][arow] = bv.x; Bs[akc+1][arow] = bv.y;
            Bs[akc+2][arow] = bv.z; Bs[akc+3][arow] = bv.w;
        }
        __syncthreads();
        #pragma unroll
        for (int kk = 0; kk < 16; ++kk) {
            float4 a = *(const float4*)&As[kk][ty*4];
            float4 b = *(const float4*)&Bs[kk][tx*4];
            acc[0][0] += a.x*b.x; acc[0][1] += a.x*b.y; acc[0][2] += a.x*b.z; acc[0][3] += a.x*b.w;
            acc[1][0] += a.y*b.x; acc[1][1] += a.y*b.y; acc[1][2] += a.y*b.z; acc[1][3] += a.y*b.w;
            acc[2][0] += a.z*b.x; acc[2][1] += a.z*b.y; acc[2][2] += a.z*b.z; acc[2][3] += a.z*b.w;
            acc[3][0] += a.w*b.x; acc[3][1] += a.w*b.y; acc[3][2] += a.w*b.z; acc[3][3] += a.w*b.w;
        }
        __syncthreads();
    }

    int row0 = bm + ty*4, col0 = bn + tx*4;
    #pragma unroll
    for (int mm = 0; mm < 4; ++mm) {
        int r = row0 + mm;
        float4 vv = make_float4(acc[mm][0], acc[mm][1], acc[mm][2], acc[mm][3]);
        if (EPI == 2 || EPI == 3) {
            float4 bb = *(const float4*)&bias[col0];
            vv.x += bb.x; vv.y += bb.y; vv.z += bb.z; vv.w += bb.w;
        }
        if (EPI == 2) {
            vv.x = 0.5f*vv.x*(1.0f + erff(vv.x*0.70710678118f));
            vv.y = 0.5f*vv.y*(1.0f + erff(vv.y*0.70710678118f));
            vv.z = 0.5f*vv.z*(1.0f + erff(vv.z*0.70710678118f));
            vv.w = 0.5f*vv.w*(1.0f + erff(vv.w*0.70710678118f));
        }
        if (EPI == 1 || EPI == 3) {
            float4 rr = *(const float4*)&res[(size_t)r*N + col0];
            vv.x += rr.x; vv.y += rr.y; vv.z += rr.z; vv.w += rr.w;
        }
        *(float4*)&C[(size_t)r*N + col0] = vv;
    }
}

// ---------------------------------------------------------------
// fused attention row: one block per (b,h,i)
// scores -> softmax -> de/fe -> PV
// ---------------------------------------------------------------
__global__ __launch_bounds__(256) void attn_kernel(
    const float* __restrict__ qkv, const float* __restrict__ sp,
    float* __restrict__ obuf, float* __restrict__ de_acc, float* __restrict__ fe_acc)
{
    __shared__ float q_s[DH_];
    __shared__ float sc[S_];
    __shared__ float ds[S_];
    __shared__ float red[4];
    __shared__ float ored[4][DH_];

    int bid = blockIdx.x;
    int i = bid & (S_ - 1);
    int h = (bid >> 10) % H_;
    int b = bid / (S_ * H_);
    int tid = threadIdx.x;

    const float* qrow = qkv + (size_t)(b*S_ + i)*D3_ + h*DH_;
    if (tid < DH_) q_s[tid] = qrow[tid];
    float si0 = sp[(b*S_+i)*3+0], si1 = sp[(b*S_+i)*3+1], si2 = sp[(b*S_+i)*3+2];
    __syncthreads();

    // pass 1: scores + dists + local max
    float lmax = -1e30f;
    for (int j = tid; j <= i; j += 256) {
        const float* krow = qkv + (size_t)(b*S_ + j)*D3_ + D_ + h*DH_;
        float dot = 0.0f;
        #pragma unroll
        for (int d = 0; d < DH_; d += 4) {
            float4 kv = *(const float4*)&krow[d];
            dot += q_s[d]*kv.x + q_s[d+1]*kv.y + q_s[d+2]*kv.z + q_s[d+3]*kv.w;
        }
        float e0 = si0 - sp[(b*S_+j)*3+0];
        float e1 = si1 - sp[(b*S_+j)*3+1];
        float e2 = si2 - sp[(b*S_+j)*3+2];
        float dist = sqrtf(e0*e0 + e1*e1 + e2*e2 + 1e-12f);
        ds[j] = dist;
        float s = dot*0.125f - dist;   // PEN=1
        sc[j] = s;
        lmax = fmaxf(lmax, s);
    }
    float m = block_max(lmax, red);

    // pass 2: exp + sum
    float lsum = 0.0f;
    for (int j = tid; j <= i; j += 256) {
        float e = __expf(sc[j] - m);
        sc[j] = e;
        lsum += e;
    }
    float ssum = block_sum(lsum, red);
    float inv = 1.0f / ssum;

    // pass 3: normalize + de/fe
    float de_l = 0.0f, fe_l = 0.0f;
    for (int j = tid; j <= i; j += 256) {
        float w = sc[j] * inv;
        sc[j] = w;
        de_l += w * ds[j];
        fe_l -= w * __logf(w + 1e-9f);
    }
    float de_b = block_sum(de_l, red);
    float fe_b = block_sum(fe_l, red);
    if (tid == 0) {
        atomicAdd(de_acc, de_b * (1.0f/49152.0f));   // mean over B*H*T
        atomicAdd(fe_acc, fe_b * (1.0f/49152.0f));
    }
    __syncthreads();

    // PV: wave g handles j = g mod 4; lanes = head dim (coalesced)
    int g = tid >> 6, d = tid & 63;
    float o = 0.0f;
    for (int j = g; j <= i; j += 4) {
        o += sc[j] * qkv[(size_t)(b*S_ + j)*D3_ + 2*D_ + h*DH_ + d];
    }
    ored[g][d] = o;
    __syncthreads();
    if (tid < DH_) {
        float oo = ored[0][tid] + ored[1][tid] + ored[2][tid] + ored[3][tid];
        obuf[(size_t)(b*S_ + i)*D_ + h*DH_ + tid] = oo;
    }
}

// ---------------------------------------------------------------
// cross-entropy: one block per row (V=256 -> one logit per thread)
// ---------------------------------------------------------------
__global__ __launch_bounds__(256) void ce_kernel(
    const float* __restrict__ logits, const int* __restrict__ targets,
    float* __restrict__ ce_acc)
{
    __shared__ float red[4];
    int r = blockIdx.x, tid = threadIdx.x;
    float x = logits[(size_t)r*V_ + tid];
    float m = block_max(x, red);
    float e = __expf(x - m);
    float s = block_sum(e, red);
    if (tid == 0) {
        float lse = m + __logf(s);
        float tl = logits[(size_t)r*V_ + targets[r]];
        atomicAdd(ce_acc, (lse - tl) * (1.0f/(float)BS_));
    }
}

// ---------------------------------------------------------------
// repulsion: 256 blocks x 256 threads, one (i,j) pair per thread
// ---------------------------------------------------------------
__global__ __launch_bounds__(256) void rep_kernel(
    const float* __restrict__ tp, float* __restrict__ rep_acc)
{
    __shared__ float red[4];
    int i = blockIdx.x, j = threadIdx.x;
    float val = 0.0f;
    if (i != j) {
        float d0 = tp[i*3+0]-tp[j*3+0];
        float d1 = tp[i*3+1]-tp[j*3+1];
        float d2 = tp[i*3+2]-tp[j*3+2];
        float dm = sqrtf(d0*d0 + d1*d1 + d2*d2 + 1e-12f);
        val = 1.0f/(dm + 1e-4f);
    }
    float s = block_sum(val, red);
    if (j == 0) atomicAdd(rep_acc, s);
}

// ---------------------------------------------------------------
// finalize: loss = ce + 0.01*(de+fe+rep); write 4 scalars
// acc: [0]=de [1]=fe [2]=rep_sum [3]=ce
// ---------------------------------------------------------------
__global__ void finalize_kernel(float* __restrict__ out4, const float* __restrict__ acc) {
    if (threadIdx.x == 0) {
        float de = acc[0], fe = acc[1];
        float rep = acc[2] * (1.0f/(256.0f*255.0f));
        float ce = acc[3];
        out4[0] = ce + 0.01f*de + 0.01f*fe + 0.01f*rep;
        out4[1] = de;
        out4[2] = fe;
        out4[3] = rep;
    }
}

// ---------------------------------------------------------------
extern "C" void kernel_launch(void* const* d_in, const int* in_sizes, int n_in,
                              void* d_out, int out_size, void* d_ws, size_t ws_size,
                              hipStream_t stream)
{
    const int*   idx      = (const int*)  d_in[0];
    const int*   targets  = (const int*)  d_in[1];
    const float* tok_emb  = (const float*)d_in[2];
    const float* pos_emb  = (const float*)d_in[3];
    const float* tok_pos  = (const float*)d_in[4];
    const float* pproj    = (const float*)d_in[5];
    const float* ln1_g    = (const float*)d_in[6];
    const float* ln1_b    = (const float*)d_in[7];
    const float* Wqkv     = (const float*)d_in[8];
    const float* Wproj    = (const float*)d_in[9];
    const float* ln2_g    = (const float*)d_in[10];
    const float* ln2_b    = (const float*)d_in[11];
    const float* Wff1     = (const float*)d_in[12];
    const float* bff1     = (const float*)d_in[13];
    const float* Wff2     = (const float*)d_in[14];
    const float* bff2     = (const float*)d_in[15];
    const float* lnf_g    = (const float*)d_in[16];
    const float* lnf_b    = (const float*)d_in[17];

    float* out = (float*)d_out;              // logits [BSV_] then 4 scalars

    // workspace layout (floats)
    float* wsf  = (float*)d_ws;
    float* acc  = wsf;                       // 8
    float* sp   = wsf + 8;                   // BS_*3 = 12288
    float* x    = sp + (size_t)BS_*3;        // BS_*D_
    float* hb   = x  + (size_t)BS_*D_;       // BS_*D_ (shared: h / attn-out)
    float* qkvb = hb + (size_t)BS_*D_;       // BS_*D3_
    float* ffb  = qkvb + (size_t)BS_*D3_;    // BS_*D4_

    zero_kernel<<<1, 64, 0, stream>>>(acc);

    embed_kernel<<<BS_, 256, 0, stream>>>(idx, tok_emb, pos_emb, tok_pos, pproj, x, sp);

    for (int l = 0; l < L_; ++l) {
        ln_kernel<<<BS_, 256, 0, stream>>>(x, ln1_g + l*D_, ln1_b + l*D_, hb);

        gemm_kernel<0,false><<<dim3(D3_/64, BS_/64), 256, 0, stream>>>(
            hb, Wqkv + (size_t)l*D_*D3_, nullptr, nullptr, qkvb, BS_, D3_, D_);

        attn_kernel<<<B_*H_*S_, 256, 0, stream>>>(qkvb, sp, hb, &acc[0], &acc[1]);

        gemm_kernel<1,false><<<dim3(D_/64, BS_/64), 256, 0, stream>>>(
            hb, Wproj + (size_t)l*D_*D_, nullptr, x, x, BS_, D_, D_);

        ln_kernel<<<BS_, 256, 0, stream>>>(x, ln2_g + l*D_, ln2_b + l*D_, hb);

        gemm_kernel<2,false><<<dim3(D4_/64, BS_/64), 256, 0, stream>>>(
            hb, Wff1 + (size_t)l*D_*D4_, bff1 + l*D4_, nullptr, ffb, BS_, D4_, D_);

        gemm_kernel<3,false><<<dim3(D_/64, BS_/64), 256, 0, stream>>>(
            ffb, Wff2 + (size_t)l*D4_*D_, bff2 + l*D_, x, x, BS_, D_, D4_);
    }

    ln_kernel<<<BS_, 256, 0, stream>>>(x, lnf_g, lnf_b, hb);

    // tied lm_head: logits = h @ token_emb^T   (B as [N,K])
    gemm_kernel<0,true><<<dim3(V_/64, BS_/64), 256, 0, stream>>>(
        hb, tok_emb, nullptr, nullptr, out, BS_, V_, D_);

    ce_kernel<<<BS_, 256, 0, stream>>>(out, targets, &acc[3]);
    rep_kernel<<<V_, 256, 0, stream>>>(tok_pos, &acc[2]);
    finalize_kernel<<<1, 64, 0, stream>>>(out + BSV_, acc);
}

// Round 2
// 5108.451 us; speedup vs baseline: 2.3912x; 2.3912x over previous
//
#include <hip/hip_runtime.h>
#include <math.h>

// ---- problem constants ----
#define V_   256
#define S_   1024
#define D_   768
#define H_   12
#define L_   4
#define DS_  3
#define B_   4
#define DH_  64        // D_/H_
#define BS_  (B_*S_)   // 4096
#define D3_  (3*D_)    // 2304
#define D4_  (4*D_)    // 3072
#define BSV_ (BS_*V_)  // 1048576

// ---------------------------------------------------------------
// block-wide reductions (256 threads = 4 waves of 64)
// ---------------------------------------------------------------
__device__ __forceinline__ float block_sum(float v, float* red) {
    #pragma unroll
    for (int m = 32; m > 0; m >>= 1) v += __shfl_xor(v, m, 64);
    int wid = threadIdx.x >> 6;
    __syncthreads();                       // protect red[] reuse
    if ((threadIdx.x & 63) == 0) red[wid] = v;
    __syncthreads();
    return red[0] + red[1] + red[2] + red[3];
}

__device__ __forceinline__ float block_max(float v, float* red) {
    #pragma unroll
    for (int m = 32; m > 0; m >>= 1) v = fmaxf(v, __shfl_xor(v, m, 64));
    int wid = threadIdx.x >> 6;
    __syncthreads();
    if ((threadIdx.x & 63) == 0) red[wid] = v;
    __syncthreads();
    return fmaxf(fmaxf(red[0], red[1]), fmaxf(red[2], red[3]));
}

// ---------------------------------------------------------------
__global__ void zero_kernel(float* acc) {
    if (threadIdx.x < 8) acc[threadIdx.x] = 0.0f;
}

// ---------------------------------------------------------------
// embedding: x = tok_emb[idx] + pos_emb[t] + sp @ pproj ; stash sp
// ---------------------------------------------------------------
__global__ __launch_bounds__(256) void embed_kernel(
    const int* __restrict__ idx, const float* __restrict__ tok_emb,
    const float* __restrict__ pos_emb, const float* __restrict__ tok_pos,
    const float* __restrict__ pproj, float* __restrict__ x, float* __restrict__ sp)
{
    int r = blockIdx.x;                 // b*S + t
    int t = r & (S_ - 1);
    int id = idx[r];
    float s0 = tok_pos[id*3+0], s1 = tok_pos[id*3+1], s2 = tok_pos[id*3+2];
    if (threadIdx.x == 0) { sp[r*3+0] = s0; sp[r*3+1] = s1; sp[r*3+2] = s2; }
    for (int d = threadIdx.x; d < D_; d += 256) {
        x[(size_t)r*D_ + d] = tok_emb[(size_t)id*D_ + d] + pos_emb[(size_t)t*D_ + d]
                            + s0*pproj[d] + s1*pproj[D_+d] + s2*pproj[2*D_+d];
    }
}

// ---------------------------------------------------------------
// layernorm, one block (256 thr) per row of 768
// ---------------------------------------------------------------
__global__ __launch_bounds__(256) void ln_kernel(
    const float* __restrict__ in, const float* __restrict__ g,
    const float* __restrict__ b, float* __restrict__ out)
{
    __shared__ float red[4];
    int r = blockIdx.x, tid = threadIdx.x;
    const float* p = in + (size_t)r*D_;
    float v0 = p[tid], v1 = p[tid+256], v2 = p[tid+512];
    float s = block_sum(v0+v1+v2, red);
    float mean = s * (1.0f/768.0f);
    float d0 = v0-mean, d1 = v1-mean, d2 = v2-mean;
    float var = block_sum(d0*d0+d1*d1+d2*d2, red) * (1.0f/768.0f);
    float inv = rsqrtf(var + 1e-5f);
    float* o = out + (size_t)r*D_;
    o[tid    ] = d0*inv*g[tid    ] + b[tid    ];
    o[tid+256] = d1*inv*g[tid+256] + b[tid+256];
    o[tid+512] = d2*inv*g[tid+512] + b[tid+512];
}

// ---------------------------------------------------------------
// f32 GEMM  C[M,N] = A[M,K] @ B[K,N]   (BT: B is [N,K], use B^T)
// 64x64 tile, 256 threads, 4x4 per thread, K-tile 16
// EPI: 0=none 1=+res 2=+bias,gelu 3=+bias,+res
// ---------------------------------------------------------------
template<int EPI, bool BT>
__global__ __launch_bounds__(256) void gemm_kernel(
    const float* __restrict__ A, const float* __restrict__ Bm,
    const float* __restrict__ bias, const float* __restrict__ res,
    float* __restrict__ C, int M, int N, int K)
{
    __shared__ float As[16][68];
    __shared__ float Bs[16][68];
    int tid = threadIdx.x;
    int tx = tid & 15, ty = tid >> 4;
    int bn = blockIdx.x * 64, bm = blockIdx.y * 64;
    float acc[4][4] = {};

    int arow = tid >> 2;            // 0..63
    int akc  = (tid & 3) * 4;       // 0,4,8,12
    int kb   = tid >> 4;            // 0..15  (NN B-load row)
    int nb   = (tid & 15) * 4;      // 0..60  (NN B-load col)

    for (int k0 = 0; k0 < K; k0 += 16) {
        float4 av = *(const float4*)&A[(size_t)(bm+arow)*K + k0 + akc];
        As[akc+0][arow] = av.x; As[akc+1][arow] = av.y;
        As[akc+2][arow] = av.z; As[akc+3][arow] = av.w;
        if (!BT) {
            float4 bv = *(const float4*)&Bm[(size_t)(k0+kb)*N + bn + nb];
            *(float4*)&Bs[kb][nb] = bv;
        } else {
            float4 bv = *(const float4*)&Bm[(size_t)(bn+arow)*K + k0 + akc];
            Bs[akc+0][arow] = bv.x; Bs[akc+1][arow] = bv.y;
            Bs[akc+2][arow] = bv.z; Bs[akc+3][arow] = bv.w;
        }
        __syncthreads();
        #pragma unroll
        for (int kk = 0; kk < 16; ++kk) {
            float4 a = *(const float4*)&As[kk][ty*4];
            float4 b = *(const float4*)&Bs[kk][tx*4];
            acc[0][0] += a.x*b.x; acc[0][1] += a.x*b.y; acc[0][2] += a.x*b.z; acc[0][3] += a.x*b.w;
            acc[1][0] += a.y*b.x; acc[1][1] += a.y*b.y; acc[1][2] += a.y*b.z; acc[1][3] += a.y*b.w;
            acc[2][0] += a.z*b.x; acc[2][1] += a.z*b.y; acc[2][2] += a.z*b.z; acc[2][3] += a.z*b.w;
            acc[3][0] += a.w*b.x; acc[3][1] += a.w*b.y; acc[3][2] += a.w*b.z; acc[3][3] += a.w*b.w;
        }
        __syncthreads();
    }

    int row0 = bm + ty*4, col0 = bn + tx*4;
    #pragma unroll
    for (int mm = 0; mm < 4; ++mm) {
        int r = row0 + mm;
        float4 vv = make_float4(acc[mm][0], acc[mm][1], acc[mm][2], acc[mm][3]);
        if (EPI == 2 || EPI == 3) {
            float4 bb = *(const float4*)&bias[col0];
            vv.x += bb.x; vv.y += bb.y; vv.z += bb.z; vv.w += bb.w;
        }
        if (EPI == 2) {
            vv.x = 0.5f*vv.x*(1.0f + erff(vv.x*0.70710678118f));
            vv.y = 0.5f*vv.y*(1.0f + erff(vv.y*0.70710678118f));
            vv.z = 0.5f*vv.z*(1.0f + erff(vv.z*0.70710678118f));
            vv.w = 0.5f*vv.w*(1.0f + erff(vv.w*0.70710678118f));
        }
        if (EPI == 1 || EPI == 3) {
            float4 rr = *(const float4*)&res[(size_t)r*N + col0];
            vv.x += rr.x; vv.y += rr.y; vv.z += rr.z; vv.w += rr.w;
        }
        *(float4*)&C[(size_t)r*N + col0] = vv;
    }
}

// ---------------------------------------------------------------
// flash-style tiled attention, f32.
// block = 64 query rows of one (b,h); 256 thr = 4 waves.
// wave w owns rows w*16..w*16+15; lane l: g=l>>4 (k/d group), qq=l&15.
// LDS: Qs[64][68], KtPs[64][68] (K^T aliased with P), Vs[64][68].
// online softmax with running M, Z, Sde=sum(e*dist), Sws=sum(e*score).
//   de_row = Sde/Z ; fe_row = M + log(Z) - Sws/Z
// ---------------------------------------------------------------
#define FMA16(A, q1, base) do {                                              \
    const float* _bp = (base);                                               \
    float4 k0 = *(const float4*)&_bp[0];                                     \
    float4 k1 = *(const float4*)&_bp[4];                                     \
    float4 k2 = *(const float4*)&_bp[8];                                     \
    float4 k3 = *(const float4*)&_bp[12];                                    \
    A[0]  += (q1)*k0.x; A[1]  += (q1)*k0.y; A[2]  += (q1)*k0.z; A[3]  += (q1)*k0.w; \
    A[4]  += (q1)*k1.x; A[5]  += (q1)*k1.y; A[6]  += (q1)*k1.z; A[7]  += (q1)*k1.w; \
    A[8]  += (q1)*k2.x; A[9]  += (q1)*k2.y; A[10] += (q1)*k2.z; A[11] += (q1)*k2.w; \
    A[12] += (q1)*k3.x; A[13] += (q1)*k3.y; A[14] += (q1)*k3.z; A[15] += (q1)*k3.w; \
} while(0)

__global__ __launch_bounds__(256) void attn_tile_kernel(
    const float* __restrict__ qkv, const float* __restrict__ sp,
    float* __restrict__ obuf, float* __restrict__ de_acc, float* __restrict__ fe_acc)
{
    __shared__ float Qs[64][68];
    __shared__ float KtPs[64][68];   // K^T [d][k] during scores; P [q][k] during PV
    __shared__ float Vs[64][68];     // [k][d]
    __shared__ float sps[64][4];

    int tile = blockIdx.x & 15;            // S/64
    int h = (blockIdx.x >> 4) % H_;
    int b = blockIdx.x / (16 * H_);
    int i0 = tile * 64;

    int tid = threadIdx.x;
    int w = tid >> 6;
    int l = tid & 63;
    int g = l >> 4;
    int g16 = g * 16;
    int qq = l & 15;
    int row = w * 16 + qq;                 // query row within tile
    int i = i0 + row;                      // global query index
    size_t qkv_base = ((size_t)b * S_) * D3_;

    // stage Q tile
    {
        int r = tid >> 2, c = (tid & 3) * 16;
        const float* src = qkv + qkv_base + (size_t)(i0 + r) * D3_ + h * DH_ + c;
        #pragma unroll
        for (int c4 = 0; c4 < 16; c4 += 4)
            *(float4*)&Qs[r][c + c4] = *(const float4*)(src + c4);
    }
    float sq0 = sp[(b*S_+i)*3+0], sq1 = sp[(b*S_+i)*3+1], sq2 = sp[(b*S_+i)*3+2];
    __syncthreads();

    float M = -1e30f, Z = 0.f, Sde = 0.f, Sws = 0.f;
    float O[16];
    #pragma unroll
    for (int d = 0; d < 16; ++d) O[d] = 0.f;

    for (int j0 = 0; j0 <= i0; j0 += 64) {
        __syncthreads();   // prev tile's PV done before overwriting Kt/Vs
        // stage K^T, V, sps
        {
            int r = tid >> 2, c = (tid & 3) * 16;
            const float* ksrc = qkv + qkv_base + (size_t)(j0 + r) * D3_ + D_ + h * DH_ + c;
            #pragma unroll
            for (int c4 = 0; c4 < 16; c4 += 4) {
                float4 kv = *(const float4*)(ksrc + c4);
                KtPs[c+c4+0][r] = kv.x; KtPs[c+c4+1][r] = kv.y;
                KtPs[c+c4+2][r] = kv.z; KtPs[c+c4+3][r] = kv.w;
            }
            const float* vsrc = qkv + qkv_base + (size_t)(j0 + r) * D3_ + 2*D_ + h * DH_ + c;
            #pragma unroll
            for (int c4 = 0; c4 < 16; c4 += 4)
                *(float4*)&Vs[r][c + c4] = *(const float4*)(vsrc + c4);
            if (tid < 64) {
                sps[tid][0] = sp[(b*S_+j0+tid)*3+0];
                sps[tid][1] = sp[(b*S_+j0+tid)*3+1];
                sps[tid][2] = sp[(b*S_+j0+tid)*3+2];
            }
        }
        __syncthreads();

        // scores: acc[kk] = Q[row] . K[j0+g16+kk]
        float acc[16];
        #pragma unroll
        for (int kk = 0; kk < 16; ++kk) acc[kk] = 0.f;
        for (int d = 0; d < 64; d += 4) {
            float4 qv = *(const float4*)&Qs[row][d];
            FMA16(acc, qv.x, &KtPs[d+0][g16]);
            FMA16(acc, qv.y, &KtPs[d+1][g16]);
            FMA16(acc, qv.z, &KtPs[d+2][g16]);
            FMA16(acc, qv.w, &KtPs[d+3][g16]);
        }
        __syncthreads();   // all waves done reading K^T before P overwrites it

        // dist penalty + causal mask
        float dstv[16];
        int jb = j0 + g16;
        #pragma unroll
        for (int kk = 0; kk < 16; ++kk) {
            float e0 = sq0 - sps[g16+kk][0];
            float e1 = sq1 - sps[g16+kk][1];
            float e2 = sq2 - sps[g16+kk][2];
            float dist = sqrtf(e0*e0 + e1*e1 + e2*e2 + 1e-12f);
            dstv[kk] = dist;
            float s = acc[kk] * 0.125f - dist;
            acc[kk] = (jb + kk <= i) ? s : -1e30f;
        }

        // row max across lane (16) then across the 4 g-lanes
        float mt = acc[0];
        #pragma unroll
        for (int kk = 1; kk < 16; ++kk) mt = fmaxf(mt, acc[kk]);
        mt = fmaxf(mt, __shfl_xor(mt, 16, 64));
        mt = fmaxf(mt, __shfl_xor(mt, 32, 64));
        float Mnew = fmaxf(M, mt);
        float scale = __expf(M - Mnew);

        float zl = 0.f, del = 0.f, wsl = 0.f;
        float ev[16];
        #pragma unroll
        for (int kk = 0; kk < 16; ++kk) {
            float e = __expf(acc[kk] - Mnew);
            ev[kk] = e;
            zl  += e;
            del += e * dstv[kk];
            wsl += e * acc[kk];
        }
        // stash P (aliases Kt region; rows are wave-private)
        *(float4*)&KtPs[row][g16+ 0] = make_float4(ev[0], ev[1], ev[2], ev[3]);
        *(float4*)&KtPs[row][g16+ 4] = make_float4(ev[4], ev[5], ev[6], ev[7]);
        *(float4*)&KtPs[row][g16+ 8] = make_float4(ev[8], ev[9], ev[10], ev[11]);
        *(float4*)&KtPs[row][g16+12] = make_float4(ev[12], ev[13], ev[14], ev[15]);

        // cross-g sums
        zl  += __shfl_xor(zl, 16, 64);  zl  += __shfl_xor(zl, 32, 64);
        del += __shfl_xor(del, 16, 64); del += __shfl_xor(del, 32, 64);
        wsl += __shfl_xor(wsl, 16, 64); wsl += __shfl_xor(wsl, 32, 64);

        Z   = Z  * scale + zl;
        Sde = Sde* scale + del;
        Sws = Sws* scale + wsl;
        #pragma unroll
        for (int dd = 0; dd < 16; ++dd) O[dd] *= scale;
        M = Mnew;

        __syncthreads();   // P visible before PV

        // PV: O[dd] += sum_k P[row][k] * V[k][g16+dd]
        for (int k = 0; k < 64; k += 4) {
            float4 pw = *(const float4*)&KtPs[row][k];
            FMA16(O, pw.x, &Vs[k+0][g16]);
            FMA16(O, pw.y, &Vs[k+1][g16]);
            FMA16(O, pw.z, &Vs[k+2][g16]);
            FMA16(O, pw.w, &Vs[k+3][g16]);
        }
    }

    // finalize row stats
    float de_row = Sde / Z;
    float fe_row = M + __logf(Z) - Sws / Z;
    float dv = (g == 0) ? de_row : 0.f;
    float fv = (g == 0) ? fe_row : 0.f;
    #pragma unroll
    for (int m = 32; m > 0; m >>= 1) { dv += __shfl_xor(dv, m, 64); fv += __shfl_xor(fv, m, 64); }
    if (l == 0) {
        atomicAdd(de_acc, dv * (1.0f/49152.0f));
        atomicAdd(fe_acc, fv * (1.0f/49152.0f));
    }

    // write O
    float invz = 1.0f / Z;
    float* op = obuf + (size_t)(b*S_ + i) * D_ + h * DH_ + g16;
    #pragma unroll
    for (int dd = 0; dd < 16; dd += 4) {
        *(float4*)&op[dd] = make_float4(O[dd]*invz, O[dd+1]*invz, O[dd+2]*invz, O[dd+3]*invz);
    }
}

// ---------------------------------------------------------------
// cross-entropy: one block per row (V=256 -> one logit per thread)
// ---------------------------------------------------------------
__global__ __launch_bounds__(256) void ce_kernel(
    const float* __restrict__ logits, const int* __restrict__ targets,
    float* __restrict__ ce_acc)
{
    __shared__ float red[4];
    int r = blockIdx.x, tid = threadIdx.x;
    float x = logits[(size_t)r*V_ + tid];
    float m = block_max(x, red);
    float e = __expf(x - m);
    float s = block_sum(e, red);
    if (tid == 0) {
        float lse = m + __logf(s);
        float tl = logits[(size_t)r*V_ + targets[r]];
        atomicAdd(ce_acc, (lse - tl) * (1.0f/(float)BS_));
    }
}

// ---------------------------------------------------------------
// repulsion: 256 blocks x 256 threads
// ---------------------------------------------------------------
__global__ __launch_bounds__(256) void rep_kernel(
    const float* __restrict__ tp, float* __restrict__ rep_acc)
{
    __shared__ float red[4];
    int i = blockIdx.x, j = threadIdx.x;
    float val = 0.0f;
    if (i != j) {
        float d0 = tp[i*3+0]-tp[j*3+0];
        float d1 = tp[i*3+1]-tp[j*3+1];
        float d2 = tp[i*3+2]-tp[j*3+2];
        float dm = sqrtf(d0*d0 + d1*d1 + d2*d2 + 1e-12f);
        val = 1.0f/(dm + 1e-4f);
    }
    float s = block_sum(val, red);
    if (j == 0) atomicAdd(rep_acc, s);
}

// ---------------------------------------------------------------
__global__ void finalize_kernel(float* __restrict__ out4, const float* __restrict__ acc) {
    if (threadIdx.x == 0) {
        float de = acc[0], fe = acc[1];
        float rep = acc[2] * (1.0f/(256.0f*255.0f));
        float ce = acc[3];
        out4[0] = ce + 0.01f*de + 0.01f*fe + 0.01f*rep;
        out4[1] = de;
        out4[2] = fe;
        out4[3] = rep;
    }
}

// ---------------------------------------------------------------
extern "C" void kernel_launch(void* const* d_in, const int* in_sizes, int n_in,
                              void* d_out, int out_size, void* d_ws, size_t ws_size,
                              hipStream_t stream)
{
    const int*   idx      = (const int*)  d_in[0];
    const int*   targets  = (const int*)  d_in[1];
    const float* tok_emb  = (const float*)d_in[2];
    const float* pos_emb  = (const float*)d_in[3];
    const float* tok_pos  = (const float*)d_in[4];
    const float* pproj    = (const float*)d_in[5];
    const float* ln1_g    = (const float*)d_in[6];
    const float* ln1_b    = (const float*)d_in[7];
    const float* Wqkv     = (const float*)d_in[8];
    const float* Wproj    = (const float*)d_in[9];
    const float* ln2_g    = (const float*)d_in[10];
    const float* ln2_b    = (const float*)d_in[11];
    const float* Wff1     = (const float*)d_in[12];
    const float* bff1     = (const float*)d_in[13];
    const float* Wff2     = (const float*)d_in[14];
    const float* bff2     = (const float*)d_in[15];
    const float* lnf_g    = (const float*)d_in[16];
    const float* lnf_b    = (const float*)d_in[17];

    float* out = (float*)d_out;              // logits [BSV_] then 4 scalars

    // workspace layout (floats)
    float* wsf  = (float*)d_ws;
    float* acc  = wsf;                       // 8
    float* sp   = wsf + 8;                   // BS_*3
    float* x    = sp + (size_t)BS_*3;        // BS_*D_
    float* hb   = x  + (size_t)BS_*D_;       // BS_*D_ (shared: h / attn-out)
    float* qkvb = hb + (size_t)BS_*D_;       // BS_*D3_
    float* ffb  = qkvb + (size_t)BS_*D3_;    // BS_*D4_

    zero_kernel<<<1, 64, 0, stream>>>(acc);

    embed_kernel<<<BS_, 256, 0, stream>>>(idx, tok_emb, pos_emb, tok_pos, pproj, x, sp);

    for (int l = 0; l < L_; ++l) {
        ln_kernel<<<BS_, 256, 0, stream>>>(x, ln1_g + l*D_, ln1_b + l*D_, hb);

        gemm_kernel<0,false><<<dim3(D3_/64, BS_/64), 256, 0, stream>>>(
            hb, Wqkv + (size_t)l*D_*D3_, nullptr, nullptr, qkvb, BS_, D3_, D_);

        attn_tile_kernel<<<B_*H_*(S_/64), 256, 0, stream>>>(qkvb, sp, hb, &acc[0], &acc[1]);

        gemm_kernel<1,false><<<dim3(D_/64, BS_/64), 256, 0, stream>>>(
            hb, Wproj + (size_t)l*D_*D_, nullptr, x, x, BS_, D_, D_);

        ln_kernel<<<BS_, 256, 0, stream>>>(x, ln2_g + l*D_, ln2_b + l*D_, hb);

        gemm_kernel<2,false><<<dim3(D4_/64, BS_/64), 256, 0, stream>>>(
            hb, Wff1 + (size_t)l*D_*D4_, bff1 + l*D4_, nullptr, ffb, BS_, D4_, D_);

        gemm_kernel<3,false><<<dim3(D_/64, BS_/64), 256, 0, stream>>>(
            ffb, Wff2 + (size_t)l*D4_*D_, bff2 + l*D_, x, x, BS_, D_, D4_);
    }

    ln_kernel<<<BS_, 256, 0, stream>>>(x, lnf_g, lnf_b, hb);

    // tied lm_head: logits = h @ token_emb^T   (B as [N,K])
    gemm_kernel<0,true><<<dim3(V_/64, BS_/64), 256, 0, stream>>>(
        hb, tok_emb, nullptr, nullptr, out, BS_, V_, D_);

    ce_kernel<<<BS_, 256, 0, stream>>>(out, targets, &acc[3]);
    rep_kernel<<<V_, 256, 0, stream>>>(tok_pos, &acc[2]);
    finalize_kernel<<<1, 64, 0, stream>>>(out + BSV_, acc);
}

// Round 3
// 2216.068 us; speedup vs baseline: 5.5122x; 2.3052x over previous
//
#include <hip/hip_runtime.h>
#include <math.h>

// ---- problem constants ----
#define V_   256
#define S_   1024
#define D_   768
#define H_   12
#define L_   4
#define DS_  3
#define B_   4
#define DH_  64        // D_/H_
#define BS_  (B_*S_)   // 4096
#define D3_  (3*D_)    // 2304
#define D4_  (4*D_)    // 3072
#define BSV_ (BS_*V_)  // 1048576

typedef __attribute__((ext_vector_type(8))) short short8;
typedef __attribute__((ext_vector_type(4))) float f32x4;

__device__ __forceinline__ ushort f2bf(float f) {
    unsigned u = __float_as_uint(f);
    u = (u + 0x7fffu + ((u >> 16) & 1u)) >> 16;
    return (ushort)u;
}

// ---------------------------------------------------------------
// block-wide reductions (256 threads = 4 waves of 64)
// ---------------------------------------------------------------
__device__ __forceinline__ float block_sum(float v, float* red) {
    #pragma unroll
    for (int m = 32; m > 0; m >>= 1) v += __shfl_xor(v, m, 64);
    int wid = threadIdx.x >> 6;
    __syncthreads();
    if ((threadIdx.x & 63) == 0) red[wid] = v;
    __syncthreads();
    return red[0] + red[1] + red[2] + red[3];
}

__device__ __forceinline__ float block_max(float v, float* red) {
    #pragma unroll
    for (int m = 32; m > 0; m >>= 1) v = fmaxf(v, __shfl_xor(v, m, 64));
    int wid = threadIdx.x >> 6;
    __syncthreads();
    if ((threadIdx.x & 63) == 0) red[wid] = v;
    __syncthreads();
    return fmaxf(fmaxf(red[0], red[1]), fmaxf(red[2], red[3]));
}

// ---------------------------------------------------------------
__global__ void zero_kernel(float* acc) {
    if (threadIdx.x < 8) acc[threadIdx.x] = 0.0f;
}

// ---------------------------------------------------------------
// embedding: x = tok_emb[idx] + pos_emb[t] + sp @ pproj ; stash sp
// ---------------------------------------------------------------
__global__ __launch_bounds__(256) void embed_kernel(
    const int* __restrict__ idx, const float* __restrict__ tok_emb,
    const float* __restrict__ pos_emb, const float* __restrict__ tok_pos,
    const float* __restrict__ pproj, float* __restrict__ x, float* __restrict__ sp)
{
    int r = blockIdx.x;                 // b*S + t
    int t = r & (S_ - 1);
    int id = idx[r];
    float s0 = tok_pos[id*3+0], s1 = tok_pos[id*3+1], s2 = tok_pos[id*3+2];
    if (threadIdx.x == 0) { sp[r*3+0] = s0; sp[r*3+1] = s1; sp[r*3+2] = s2; }
    for (int d = threadIdx.x; d < D_; d += 256) {
        x[(size_t)r*D_ + d] = tok_emb[(size_t)id*D_ + d] + pos_emb[(size_t)t*D_ + d]
                            + s0*pproj[d] + s1*pproj[D_+d] + s2*pproj[2*D_+d];
    }
}

// ---------------------------------------------------------------
// layernorm: OUT=0 -> f32, OUT=1 -> bf16
// ---------------------------------------------------------------
template<int OUT>
__global__ __launch_bounds__(256) void ln_kernel(
    const float* __restrict__ in, const float* __restrict__ g,
    const float* __restrict__ b, void* __restrict__ outv)
{
    __shared__ float red[4];
    int r = blockIdx.x, tid = threadIdx.x;
    const float* p = in + (size_t)r*D_;
    float v0 = p[tid], v1 = p[tid+256], v2 = p[tid+512];
    float s = block_sum(v0+v1+v2, red);
    float mean = s * (1.0f/768.0f);
    float d0 = v0-mean, d1 = v1-mean, d2 = v2-mean;
    float var = block_sum(d0*d0+d1*d1+d2*d2, red) * (1.0f/768.0f);
    float inv = rsqrtf(var + 1e-5f);
    float o0 = d0*inv*g[tid    ] + b[tid    ];
    float o1 = d1*inv*g[tid+256] + b[tid+256];
    float o2 = d2*inv*g[tid+512] + b[tid+512];
    if (OUT == 0) {
        float* o = (float*)outv + (size_t)r*D_;
        o[tid] = o0; o[tid+256] = o1; o[tid+512] = o2;
    } else {
        ushort* o = (ushort*)outv + (size_t)r*D_;
        o[tid] = f2bf(o0); o[tid+256] = f2bf(o1); o[tid+512] = f2bf(o2);
    }
}

// ---------------------------------------------------------------
// f32 -> bf16 transpose: W[K][N] f32 -> Wt[N][K] bf16, 32x32 tiles
// ---------------------------------------------------------------
__global__ __launch_bounds__(256) void transpose_bf16_kernel(
    const float* __restrict__ W, ushort* __restrict__ Wt, int K, int N)
{
    __shared__ float t[32][33];
    int n0 = blockIdx.x * 32, k0 = blockIdx.y * 32;
    int tx = threadIdx.x & 31, ty = threadIdx.x >> 5;   // ty 0..7
    #pragma unroll
    for (int r = 0; r < 32; r += 8)
        t[ty+r][tx] = W[(size_t)(k0+ty+r)*N + n0 + tx];
    __syncthreads();
    #pragma unroll
    for (int r = 0; r < 32; r += 8)
        Wt[(size_t)(n0+ty+r)*K + k0 + tx] = f2bf(t[tx][ty+r]);
}

// ---------------------------------------------------------------
// bf16 MFMA GEMM: C[M,N] = A[M,K] @ Bt[N,K]^T  (both operands [row][K] bf16)
// 128x128 tile, BK=32, 4 waves, wave = 64x64 via 4x4 of 16x16x32 MFMA.
// global_load_lds (16B) staging, linear LDS dest + pre-swizzled global src;
// read-side XOR swizzle slot = kgroup ^ ((row>>1)&3) balances ds_read_b128.
// EPI: 0 = f32 C ; 1 = f32 C=acc+res ; 2 = bf16 C=gelu(acc+bias) ; 3 = f32 C=acc+bias+res
// ---------------------------------------------------------------
template<int EPI>
__global__ __launch_bounds__(256) void gemm_bf16_kernel(
    const ushort* __restrict__ A, const ushort* __restrict__ Bt,
    const float* __restrict__ bias, const float* __restrict__ res,
    void* __restrict__ Cout, int M, int N, int K)
{
    __shared__ ushort As[128*32];
    __shared__ ushort Bs[128*32];
    int tid = threadIdx.x;
    int w = tid >> 6, l = tid & 63;
    int bm = blockIdx.y * 128, bn = blockIdx.x * 128;
    int wm = (w >> 1) * 64, wn = (w & 1) * 64;

    f32x4 acc[4][4];
    #pragma unroll
    for (int i = 0; i < 4; ++i)
        #pragma unroll
        for (int j = 0; j < 4; ++j) { acc[i][j][0]=0.f; acc[i][j][1]=0.f; acc[i][j][2]=0.f; acc[i][j][3]=0.f; }

    // staging geometry: issue i covers rows (w*2+i)*16 + (l>>2), 16B slot l&3
    int rl = l >> 2;                          // 0..15
    int sg = (l & 3) ^ ((rl >> 1) & 3);       // k-group this lane fetches (pre-swizzled src)
    const ushort* ap0 = A  + (size_t)(bm + (w*2  )*16 + rl)*K + sg*8;
    const ushort* ap1 = A  + (size_t)(bm + (w*2+1)*16 + rl)*K + sg*8;
    const ushort* bp0 = Bt + (size_t)(bn + (w*2  )*16 + rl)*K + sg*8;
    const ushort* bp1 = Bt + (size_t)(bn + (w*2+1)*16 + rl)*K + sg*8;
    ushort* al0 = &As[(w*2  )*512];
    ushort* al1 = &As[(w*2+1)*512];
    ushort* bl0 = &Bs[(w*2  )*512];
    ushort* bl1 = &Bs[(w*2+1)*512];

    #define STAGE(K0) do { \
        __builtin_amdgcn_global_load_lds((const __attribute__((address_space(1))) void*)(ap0 + (K0)), (__attribute__((address_space(3))) void*)al0, 16, 0, 0); \
        __builtin_amdgcn_global_load_lds((const __attribute__((address_space(1))) void*)(ap1 + (K0)), (__attribute__((address_space(3))) void*)al1, 16, 0, 0); \
        __builtin_amdgcn_global_load_lds((const __attribute__((address_space(1))) void*)(bp0 + (K0)), (__attribute__((address_space(3))) void*)bl0, 16, 0, 0); \
        __builtin_amdgcn_global_load_lds((const __attribute__((address_space(1))) void*)(bp1 + (K0)), (__attribute__((address_space(3))) void*)bl1, 16, 0, 0); \
    } while (0)

    int lq = l & 15, lg = l >> 4;
    STAGE(0);

    for (int k0 = 0; k0 < K; k0 += 32) {
        __syncthreads();
        short8 af[4], bfv[4];
        #pragma unroll
        for (int mi = 0; mi < 4; ++mi) {
            int r = wm + mi*16 + lq;
            int ks = lg ^ ((r >> 1) & 3);
            af[mi] = *(const short8*)&As[r*32 + ks*8];
        }
        #pragma unroll
        for (int ni = 0; ni < 4; ++ni) {
            int r = wn + ni*16 + lq;
            int ks = lg ^ ((r >> 1) & 3);
            bfv[ni] = *(const short8*)&Bs[r*32 + ks*8];
        }
        #pragma unroll
        for (int mi = 0; mi < 4; ++mi)
            #pragma unroll
            for (int ni = 0; ni < 4; ++ni)
                acc[mi][ni] = __builtin_amdgcn_mfma_f32_16x16x32_bf16(af[mi], bfv[ni], acc[mi][ni], 0, 0, 0);
        __syncthreads();
        if (k0 + 32 < K) STAGE(k0 + 32);
    }
    #undef STAGE

    // epilogue: C/D map col=lane&15, row=(lane>>4)*4+q
    int lr = (l >> 4) * 4;
    #pragma unroll
    for (int mi = 0; mi < 4; ++mi) {
        #pragma unroll
        for (int ni = 0; ni < 4; ++ni) {
            int col = bn + wn + ni*16 + lq;
            int row = bm + wm + mi*16 + lr;
            #pragma unroll
            for (int q = 0; q < 4; ++q) {
                size_t o = (size_t)(row + q)*N + col;
                float v = acc[mi][ni][q];
                if (EPI == 0) {
                    ((float*)Cout)[o] = v;
                } else if (EPI == 1) {
                    ((float*)Cout)[o] = v + res[o];
                } else if (EPI == 2) {
                    float t = v + bias[col];
                    ((ushort*)Cout)[o] = f2bf(0.5f*t*(1.0f + erff(t*0.70710678118f)));
                } else {
                    ((float*)Cout)[o] = v + bias[col] + res[o];
                }
            }
        }
    }
}

// ---------------------------------------------------------------
// f32 GEMM (kept for lm_head)  C = A[M,K] @ B^T (B as [N,K])
// ---------------------------------------------------------------
template<int EPI, bool BT>
__global__ __launch_bounds__(256) void gemm_kernel(
    const float* __restrict__ A, const float* __restrict__ Bm,
    const float* __restrict__ bias, const float* __restrict__ res,
    float* __restrict__ C, int M, int N, int K)
{
    __shared__ float As[16][68];
    __shared__ float Bs[16][68];
    int tid = threadIdx.x;
    int tx = tid & 15, ty = tid >> 4;
    int bn = blockIdx.x * 64, bm = blockIdx.y * 64;
    float acc[4][4] = {};

    int arow = tid >> 2;
    int akc  = (tid & 3) * 4;
    int kb   = tid >> 4;
    int nb   = (tid & 15) * 4;

    for (int k0 = 0; k0 < K; k0 += 16) {
        float4 av = *(const float4*)&A[(size_t)(bm+arow)*K + k0 + akc];
        As[akc+0][arow] = av.x; As[akc+1][arow] = av.y;
        As[akc+2][arow] = av.z; As[akc+3][arow] = av.w;
        if (!BT) {
            float4 bv = *(const float4*)&Bm[(size_t)(k0+kb)*N + bn + nb];
            *(float4*)&Bs[kb][nb] = bv;
        } else {
            float4 bv = *(const float4*)&Bm[(size_t)(bn+arow)*K + k0 + akc];
            Bs[akc+0][arow] = bv.x; Bs[akc+1][arow] = bv.y;
            Bs[akc+2][arow] = bv.z; Bs[akc+3][arow] = bv.w;
        }
        __syncthreads();
        #pragma unroll
        for (int kk = 0; kk < 16; ++kk) {
            float4 a = *(const float4*)&As[kk][ty*4];
            float4 b = *(const float4*)&Bs[kk][tx*4];
            acc[0][0] += a.x*b.x; acc[0][1] += a.x*b.y; acc[0][2] += a.x*b.z; acc[0][3] += a.x*b.w;
            acc[1][0] += a.y*b.x; acc[1][1] += a.y*b.y; acc[1][2] += a.y*b.z; acc[1][3] += a.y*b.w;
            acc[2][0] += a.z*b.x; acc[2][1] += a.z*b.y; acc[2][2] += a.z*b.z; acc[2][3] += a.z*b.w;
            acc[3][0] += a.w*b.x; acc[3][1] += a.w*b.y; acc[3][2] += a.w*b.z; acc[3][3] += a.w*b.w;
        }
        __syncthreads();
    }

    int row0 = bm + ty*4, col0 = bn + tx*4;
    #pragma unroll
    for (int mm = 0; mm < 4; ++mm) {
        int r = row0 + mm;
        float4 vv = make_float4(acc[mm][0], acc[mm][1], acc[mm][2], acc[mm][3]);
        if (EPI == 1) {
            float4 rr = *(const float4*)&res[(size_t)r*N + col0];
            vv.x += rr.x; vv.y += rr.y; vv.z += rr.z; vv.w += rr.w;
        }
        *(float4*)&C[(size_t)r*N + col0] = vv;
    }
}

// ---------------------------------------------------------------
// flash-style tiled attention, f32 compute, bf16 O output
// ---------------------------------------------------------------
#define FMA16(A, q1, base) do {                                              \
    const float* _bp = (base);                                               \
    float4 k0 = *(const float4*)&_bp[0];                                     \
    float4 k1 = *(const float4*)&_bp[4];                                     \
    float4 k2 = *(const float4*)&_bp[8];                                     \
    float4 k3 = *(const float4*)&_bp[12];                                    \
    A[0]  += (q1)*k0.x; A[1]  += (q1)*k0.y; A[2]  += (q1)*k0.z; A[3]  += (q1)*k0.w; \
    A[4]  += (q1)*k1.x; A[5]  += (q1)*k1.y; A[6]  += (q1)*k1.z; A[7]  += (q1)*k1.w; \
    A[8]  += (q1)*k2.x; A[9]  += (q1)*k2.y; A[10] += (q1)*k2.z; A[11] += (q1)*k2.w; \
    A[12] += (q1)*k3.x; A[13] += (q1)*k3.y; A[14] += (q1)*k3.z; A[15] += (q1)*k3.w; \
} while(0)

__global__ __launch_bounds__(256) void attn_tile_kernel(
    const float* __restrict__ qkv, const float* __restrict__ sp,
    ushort* __restrict__ obuf, float* __restrict__ de_acc, float* __restrict__ fe_acc)
{
    __shared__ float Qs[64][68];
    __shared__ float KtPs[64][68];
    __shared__ float Vs[64][68];
    __shared__ float sps[64][4];

    int tile = blockIdx.x & 15;
    int h = (blockIdx.x >> 4) % H_;
    int b = blockIdx.x / (16 * H_);
    int i0 = tile * 64;

    int tid = threadIdx.x;
    int w = tid >> 6;
    int l = tid & 63;
    int g = l >> 4;
    int g16 = g * 16;
    int qq = l & 15;
    int row = w * 16 + qq;
    int i = i0 + row;
    size_t qkv_base = ((size_t)b * S_) * D3_;

    {
        int r = tid >> 2, c = (tid & 3) * 16;
        const float* src = qkv + qkv_base + (size_t)(i0 + r) * D3_ + h * DH_ + c;
        #pragma unroll
        for (int c4 = 0; c4 < 16; c4 += 4)
            *(float4*)&Qs[r][c + c4] = *(const float4*)(src + c4);
    }
    float sq0 = sp[(b*S_+i)*3+0], sq1 = sp[(b*S_+i)*3+1], sq2 = sp[(b*S_+i)*3+2];
    __syncthreads();

    float M = -1e30f, Z = 0.f, Sde = 0.f, Sws = 0.f;
    float O[16];
    #pragma unroll
    for (int d = 0; d < 16; ++d) O[d] = 0.f;

    for (int j0 = 0; j0 <= i0; j0 += 64) {
        __syncthreads();
        {
            int r = tid >> 2, c = (tid & 3) * 16;
            const float* ksrc = qkv + qkv_base + (size_t)(j0 + r) * D3_ + D_ + h * DH_ + c;
            #pragma unroll
            for (int c4 = 0; c4 < 16; c4 += 4) {
                float4 kv = *(const float4*)(ksrc + c4);
                KtPs[c+c4+0][r] = kv.x; KtPs[c+c4+1][r] = kv.y;
                KtPs[c+c4+2][r] = kv.z; KtPs[c+c4+3][r] = kv.w;
            }
            const float* vsrc = qkv + qkv_base + (size_t)(j0 + r) * D3_ + 2*D_ + h * DH_ + c;
            #pragma unroll
            for (int c4 = 0; c4 < 16; c4 += 4)
                *(float4*)&Vs[r][c + c4] = *(const float4*)(vsrc + c4);
            if (tid < 64) {
                sps[tid][0] = sp[(b*S_+j0+tid)*3+0];
                sps[tid][1] = sp[(b*S_+j0+tid)*3+1];
                sps[tid][2] = sp[(b*S_+j0+tid)*3+2];
            }
        }
        __syncthreads();

        float acc[16];
        #pragma unroll
        for (int kk = 0; kk < 16; ++kk) acc[kk] = 0.f;
        for (int d = 0; d < 64; d += 4) {
            float4 qv = *(const float4*)&Qs[row][d];
            FMA16(acc, qv.x, &KtPs[d+0][g16]);
            FMA16(acc, qv.y, &KtPs[d+1][g16]);
            FMA16(acc, qv.z, &KtPs[d+2][g16]);
            FMA16(acc, qv.w, &KtPs[d+3][g16]);
        }
        __syncthreads();

        float dstv[16];
        int jb = j0 + g16;
        #pragma unroll
        for (int kk = 0; kk < 16; ++kk) {
            float e0 = sq0 - sps[g16+kk][0];
            float e1 = sq1 - sps[g16+kk][1];
            float e2 = sq2 - sps[g16+kk][2];
            float dist = sqrtf(e0*e0 + e1*e1 + e2*e2 + 1e-12f);
            dstv[kk] = dist;
            float s = acc[kk] * 0.125f - dist;
            acc[kk] = (jb + kk <= i) ? s : -1e30f;
        }

        float mt = acc[0];
        #pragma unroll
        for (int kk = 1; kk < 16; ++kk) mt = fmaxf(mt, acc[kk]);
        mt = fmaxf(mt, __shfl_xor(mt, 16, 64));
        mt = fmaxf(mt, __shfl_xor(mt, 32, 64));
        float Mnew = fmaxf(M, mt);
        float scale = __expf(M - Mnew);

        float zl = 0.f, del = 0.f, wsl = 0.f;
        float ev[16];
        #pragma unroll
        for (int kk = 0; kk < 16; ++kk) {
            float e = __expf(acc[kk] - Mnew);
            ev[kk] = e;
            zl  += e;
            del += e * dstv[kk];
            wsl += e * acc[kk];
        }
        *(float4*)&KtPs[row][g16+ 0] = make_float4(ev[0], ev[1], ev[2], ev[3]);
        *(float4*)&KtPs[row][g16+ 4] = make_float4(ev[4], ev[5], ev[6], ev[7]);
        *(float4*)&KtPs[row][g16+ 8] = make_float4(ev[8], ev[9], ev[10], ev[11]);
        *(float4*)&KtPs[row][g16+12] = make_float4(ev[12], ev[13], ev[14], ev[15]);

        zl  += __shfl_xor(zl, 16, 64);  zl  += __shfl_xor(zl, 32, 64);
        del += __shfl_xor(del, 16, 64); del += __shfl_xor(del, 32, 64);
        wsl += __shfl_xor(wsl, 16, 64); wsl += __shfl_xor(wsl, 32, 64);

        Z   = Z  * scale + zl;
        Sde = Sde* scale + del;
        Sws = Sws* scale + wsl;
        #pragma unroll
        for (int dd = 0; dd < 16; ++dd) O[dd] *= scale;
        M = Mnew;

        __syncthreads();

        for (int k = 0; k < 64; k += 4) {
            float4 pw = *(const float4*)&KtPs[row][k];
            FMA16(O, pw.x, &Vs[k+0][g16]);
            FMA16(O, pw.y, &Vs[k+1][g16]);
            FMA16(O, pw.z, &Vs[k+2][g16]);
            FMA16(O, pw.w, &Vs[k+3][g16]);
        }
    }

    float de_row = Sde / Z;
    float fe_row = M + __logf(Z) - Sws / Z;
    float dv = (g == 0) ? de_row : 0.f;
    float fv = (g == 0) ? fe_row : 0.f;
    #pragma unroll
    for (int m = 32; m > 0; m >>= 1) { dv += __shfl_xor(dv, m, 64); fv += __shfl_xor(fv, m, 64); }
    if (l == 0) {
        atomicAdd(de_acc, dv * (1.0f/49152.0f));
        atomicAdd(fe_acc, fv * (1.0f/49152.0f));
    }

    float invz = 1.0f / Z;
    ushort t16[16];
    #pragma unroll
    for (int dd = 0; dd < 16; ++dd) t16[dd] = f2bf(O[dd] * invz);
    ushort* op = obuf + (size_t)(b*S_ + i) * D_ + h * DH_ + g16;
    *(uint4*)&op[0] = *(uint4*)&t16[0];
    *(uint4*)&op[8] = *(uint4*)&t16[8];
}

// ---------------------------------------------------------------
__global__ __launch_bounds__(256) void ce_kernel(
    const float* __restrict__ logits, const int* __restrict__ targets,
    float* __restrict__ ce_acc)
{
    __shared__ float red[4];
    int r = blockIdx.x, tid = threadIdx.x;
    float x = logits[(size_t)r*V_ + tid];
    float m = block_max(x, red);
    float e = __expf(x - m);
    float s = block_sum(e, red);
    if (tid == 0) {
        float lse = m + __logf(s);
        float tl = logits[(size_t)r*V_ + targets[r]];
        atomicAdd(ce_acc, (lse - tl) * (1.0f/(float)BS_));
    }
}

__global__ __launch_bounds__(256) void rep_kernel(
    const float* __restrict__ tp, float* __restrict__ rep_acc)
{
    __shared__ float red[4];
    int i = blockIdx.x, j = threadIdx.x;
    float val = 0.0f;
    if (i != j) {
        float d0 = tp[i*3+0]-tp[j*3+0];
        float d1 = tp[i*3+1]-tp[j*3+1];
        float d2 = tp[i*3+2]-tp[j*3+2];
        float dm = sqrtf(d0*d0 + d1*d1 + d2*d2 + 1e-12f);
        val = 1.0f/(dm + 1e-4f);
    }
    float s = block_sum(val, red);
    if (j == 0) atomicAdd(rep_acc, s);
}

__global__ void finalize_kernel(float* __restrict__ out4, const float* __restrict__ acc) {
    if (threadIdx.x == 0) {
        float de = acc[0], fe = acc[1];
        float rep = acc[2] * (1.0f/(256.0f*255.0f));
        float ce = acc[3];
        out4[0] = ce + 0.01f*de + 0.01f*fe + 0.01f*rep;
        out4[1] = de;
        out4[2] = fe;
        out4[3] = rep;
    }
}

// ---------------------------------------------------------------
extern "C" void kernel_launch(void* const* d_in, const int* in_sizes, int n_in,
                              void* d_out, int out_size, void* d_ws, size_t ws_size,
                              hipStream_t stream)
{
    const int*   idx      = (const int*)  d_in[0];
    const int*   targets  = (const int*)  d_in[1];
    const float* tok_emb  = (const float*)d_in[2];
    const float* pos_emb  = (const float*)d_in[3];
    const float* tok_pos  = (const float*)d_in[4];
    const float* pproj    = (const float*)d_in[5];
    const float* ln1_g    = (const float*)d_in[6];
    const float* ln1_b    = (const float*)d_in[7];
    const float* Wqkv     = (const float*)d_in[8];
    const float* Wproj    = (const float*)d_in[9];
    const float* ln2_g    = (const float*)d_in[10];
    const float* ln2_b    = (const float*)d_in[11];
    const float* Wff1     = (const float*)d_in[12];
    const float* bff1     = (const float*)d_in[13];
    const float* Wff2     = (const float*)d_in[14];
    const float* bff2     = (const float*)d_in[15];
    const float* lnf_g    = (const float*)d_in[16];
    const float* lnf_b    = (const float*)d_in[17];

    float* out = (float*)d_out;

    // workspace layout
    float* wsf  = (float*)d_ws;
    float* acc  = wsf;                           // 8
    float* sp   = wsf + 8;                       // 12288
    float* x    = sp + 12288;                    // BS_*D_
    float* qkv  = x + (size_t)BS_*D_;            // BS_*D3_
    ushort* hbf  = (ushort*)(qkv + (size_t)BS_*D3_);   // BS_*D_ bf16
    ushort* ffbf = hbf + (size_t)BS_*D_;               // BS_*D4_ bf16
    ushort* wqT  = ffbf + (size_t)BS_*D4_;             // D3_*D_
    ushort* wpT  = wqT + (size_t)D3_*D_;               // D_*D_
    ushort* w1T  = wpT + (size_t)D_*D_;                // D4_*D_
    ushort* w2T  = w1T + (size_t)D4_*D_;               // D_*D4_
    float* hf = qkv;   // reuse qkv buffer for lnf output (f32)

    zero_kernel<<<1, 64, 0, stream>>>(acc);
    embed_kernel<<<BS_, 256, 0, stream>>>(idx, tok_emb, pos_emb, tok_pos, pproj, x, sp);

    for (int l = 0; l < L_; ++l) {
        // weight transposes (f32 [K][N] -> bf16 [N][K])
        transpose_bf16_kernel<<<dim3(D3_/32, D_/32), 256, 0, stream>>>(Wqkv + (size_t)l*D_*D3_, wqT, D_, D3_);
        transpose_bf16_kernel<<<dim3(D_/32,  D_/32), 256, 0, stream>>>(Wproj + (size_t)l*D_*D_, wpT, D_, D_);
        transpose_bf16_kernel<<<dim3(D4_/32, D_/32), 256, 0, stream>>>(Wff1 + (size_t)l*D_*D4_, w1T, D_, D4_);
        transpose_bf16_kernel<<<dim3(D_/32, D4_/32), 256, 0, stream>>>(Wff2 + (size_t)l*D4_*D_, w2T, D4_, D_);

        ln_kernel<1><<<BS_, 256, 0, stream>>>(x, ln1_g + l*D_, ln1_b + l*D_, hbf);

        gemm_bf16_kernel<0><<<dim3(D3_/128, BS_/128), 256, 0, stream>>>(
            hbf, wqT, nullptr, nullptr, qkv, BS_, D3_, D_);

        attn_tile_kernel<<<B_*H_*(S_/64), 256, 0, stream>>>(qkv, sp, hbf, &acc[0], &acc[1]);

        gemm_bf16_kernel<1><<<dim3(D_/128, BS_/128), 256, 0, stream>>>(
            hbf, wpT, nullptr, x, x, BS_, D_, D_);

        ln_kernel<1><<<BS_, 256, 0, stream>>>(x, ln2_g + l*D_, ln2_b + l*D_, hbf);

        gemm_bf16_kernel<2><<<dim3(D4_/128, BS_/128), 256, 0, stream>>>(
            hbf, w1T, bff1 + (size_t)l*D4_, nullptr, ffbf, BS_, D4_, D_);

        gemm_bf16_kernel<3><<<dim3(D_/128, BS_/128), 256, 0, stream>>>(
            ffbf, w2T, bff2 + (size_t)l*D_, x, x, BS_, D_, D4_);
    }

    ln_kernel<0><<<BS_, 256, 0, stream>>>(x, lnf_g, lnf_b, hf);

    // tied lm_head in f32 for logit accuracy
    gemm_kernel<0,true><<<dim3(V_/64, BS_/64), 256, 0, stream>>>(
        hf, tok_emb, nullptr, nullptr, out, BS_, V_, D_);

    ce_kernel<<<BS_, 256, 0, stream>>>(out, targets, &acc[3]);
    rep_kernel<<<V_, 256, 0, stream>>>(tok_pos, &acc[2]);
    finalize_kernel<<<1, 64, 0, stream>>>(out + BSV_, acc);
}

// Round 7
// 1507.038 us; speedup vs baseline: 8.1056x; 1.4705x over previous
//
#include <hip/hip_runtime.h>
#include <math.h>

// ---- problem constants ----
#define V_   256
#define S_   1024
#define D_   768
#define H_   12
#define L_   4
#define DS_  3
#define B_   4
#define DH_  64        // D_/H_
#define BS_  (B_*S_)   // 4096
#define D3_  (3*D_)    // 2304
#define D4_  (4*D_)    // 3072
#define BSV_ (BS_*V_)  // 1048576

typedef __attribute__((ext_vector_type(8))) short short8;
typedef __attribute__((ext_vector_type(4))) float f32x4;

__device__ __forceinline__ ushort f2bf(float f) {
    unsigned u = __float_as_uint(f);
    u = (u + 0x7fffu + ((u >> 16) & 1u)) >> 16;
    return (ushort)u;
}

// ---------------------------------------------------------------
// block-wide reductions (256 threads = 4 waves of 64)
// ---------------------------------------------------------------
__device__ __forceinline__ float block_sum(float v, float* red) {
    #pragma unroll
    for (int m = 32; m > 0; m >>= 1) v += __shfl_xor(v, m, 64);
    int wid = threadIdx.x >> 6;
    __syncthreads();
    if ((threadIdx.x & 63) == 0) red[wid] = v;
    __syncthreads();
    return red[0] + red[1] + red[2] + red[3];
}

__device__ __forceinline__ float block_max(float v, float* red) {
    #pragma unroll
    for (int m = 32; m > 0; m >>= 1) v = fmaxf(v, __shfl_xor(v, m, 64));
    int wid = threadIdx.x >> 6;
    __syncthreads();
    if ((threadIdx.x & 63) == 0) red[wid] = v;
    __syncthreads();
    return fmaxf(fmaxf(red[0], red[1]), fmaxf(red[2], red[3]));
}

// ---------------------------------------------------------------
__global__ void zero_kernel(float* acc) {
    if (threadIdx.x < 8) acc[threadIdx.x] = 0.0f;
}

// ---------------------------------------------------------------
// embedding: x = tok_emb[idx] + pos_emb[t] + sp @ pproj ; stash sp
// ---------------------------------------------------------------
__global__ __launch_bounds__(256) void embed_kernel(
    const int* __restrict__ idx, const float* __restrict__ tok_emb,
    const float* __restrict__ pos_emb, const float* __restrict__ tok_pos,
    const float* __restrict__ pproj, float* __restrict__ x, float* __restrict__ sp)
{
    int r = blockIdx.x;                 // b*S + t
    int t = r & (S_ - 1);
    int id = idx[r];
    float s0 = tok_pos[id*3+0], s1 = tok_pos[id*3+1], s2 = tok_pos[id*3+2];
    if (threadIdx.x == 0) { sp[r*3+0] = s0; sp[r*3+1] = s1; sp[r*3+2] = s2; }
    for (int d = threadIdx.x; d < D_; d += 256) {
        x[(size_t)r*D_ + d] = tok_emb[(size_t)id*D_ + d] + pos_emb[(size_t)t*D_ + d]
                            + s0*pproj[d] + s1*pproj[D_+d] + s2*pproj[2*D_+d];
    }
}

// ---------------------------------------------------------------
// layernorm: OUT=0 -> f32, OUT=1 -> bf16
// ---------------------------------------------------------------
template<int OUT>
__global__ __launch_bounds__(256) void ln_kernel(
    const float* __restrict__ in, const float* __restrict__ g,
    const float* __restrict__ b, void* __restrict__ outv)
{
    __shared__ float red[4];
    int r = blockIdx.x, tid = threadIdx.x;
    const float* p = in + (size_t)r*D_;
    float v0 = p[tid], v1 = p[tid+256], v2 = p[tid+512];
    float s = block_sum(v0+v1+v2, red);
    float mean = s * (1.0f/768.0f);
    float d0 = v0-mean, d1 = v1-mean, d2 = v2-mean;
    float var = block_sum(d0*d0+d1*d1+d2*d2, red) * (1.0f/768.0f);
    float inv = rsqrtf(var + 1e-5f);
    float o0 = d0*inv*g[tid    ] + b[tid    ];
    float o1 = d1*inv*g[tid+256] + b[tid+256];
    float o2 = d2*inv*g[tid+512] + b[tid+512];
    if (OUT == 0) {
        float* o = (float*)outv + (size_t)r*D_;
        o[tid] = o0; o[tid+256] = o1; o[tid+512] = o2;
    } else {
        ushort* o = (ushort*)outv + (size_t)r*D_;
        o[tid] = f2bf(o0); o[tid+256] = f2bf(o1); o[tid+512] = f2bf(o2);
    }
}

// ---------------------------------------------------------------
// f32 -> bf16 transpose: W[K][N] f32 -> Wt[N][K] bf16, 32x32 tiles
// ---------------------------------------------------------------
__global__ __launch_bounds__(256) void transpose_bf16_kernel(
    const float* __restrict__ W, ushort* __restrict__ Wt, int K, int N)
{
    __shared__ float t[32][33];
    int n0 = blockIdx.x * 32, k0 = blockIdx.y * 32;
    int tx = threadIdx.x & 31, ty = threadIdx.x >> 5;   // ty 0..7
    #pragma unroll
    for (int r = 0; r < 32; r += 8)
        t[ty+r][tx] = W[(size_t)(k0+ty+r)*N + n0 + tx];
    __syncthreads();
    #pragma unroll
    for (int r = 0; r < 32; r += 8)
        Wt[(size_t)(n0+ty+r)*K + k0 + tx] = f2bf(t[tx][ty+r]);
}

// ---------------------------------------------------------------
// bf16 MFMA GEMM: C[M,N] = A[M,K] @ Bt[N,K]^T  (both operands [row][K] bf16)
// 128x128 tile, BK=32, 4 waves, wave = 64x64 via 4x4 of 16x16x32 MFMA.
// EPI: 0 = f32 C ; 1 = f32 C=acc+res ; 2 = bf16 C=gelu(acc+bias) ;
//      3 = f32 C=acc+bias+res ; 4 = qkv split (q,k bf16 -> Cout[row][1536],
//          v transposed bf16 -> aux[(b*768+rel)][t])
// ---------------------------------------------------------------
template<int EPI>
__global__ __launch_bounds__(256) void gemm_bf16_kernel(
    const ushort* __restrict__ A, const ushort* __restrict__ Bt,
    const float* __restrict__ bias, const float* __restrict__ res,
    void* __restrict__ Cout, void* __restrict__ aux, int M, int N, int K)
{
    __shared__ ushort As[128*32];
    __shared__ ushort Bs[128*32];
    int tid = threadIdx.x;
    int w = tid >> 6, l = tid & 63;
    int bm = blockIdx.y * 128, bn = blockIdx.x * 128;
    int wm = (w >> 1) * 64, wn = (w & 1) * 64;

    f32x4 acc[4][4];
    #pragma unroll
    for (int i = 0; i < 4; ++i)
        #pragma unroll
        for (int j = 0; j < 4; ++j) { acc[i][j][0]=0.f; acc[i][j][1]=0.f; acc[i][j][2]=0.f; acc[i][j][3]=0.f; }

    int rl = l >> 2;                          // 0..15
    int sg = (l & 3) ^ ((rl >> 1) & 3);       // pre-swizzled src k-group
    const ushort* ap0 = A  + (size_t)(bm + (w*2  )*16 + rl)*K + sg*8;
    const ushort* ap1 = A  + (size_t)(bm + (w*2+1)*16 + rl)*K + sg*8;
    const ushort* bp0 = Bt + (size_t)(bn + (w*2  )*16 + rl)*K + sg*8;
    const ushort* bp1 = Bt + (size_t)(bn + (w*2+1)*16 + rl)*K + sg*8;
    ushort* al0 = &As[(w*2  )*512];
    ushort* al1 = &As[(w*2+1)*512];
    ushort* bl0 = &Bs[(w*2  )*512];
    ushort* bl1 = &Bs[(w*2+1)*512];

    #define STAGE(K0) do { \
        __builtin_amdgcn_global_load_lds((const __attribute__((address_space(1))) void*)(ap0 + (K0)), (__attribute__((address_space(3))) void*)al0, 16, 0, 0); \
        __builtin_amdgcn_global_load_lds((const __attribute__((address_space(1))) void*)(ap1 + (K0)), (__attribute__((address_space(3))) void*)al1, 16, 0, 0); \
        __builtin_amdgcn_global_load_lds((const __attribute__((address_space(1))) void*)(bp0 + (K0)), (__attribute__((address_space(3))) void*)bl0, 16, 0, 0); \
        __builtin_amdgcn_global_load_lds((const __attribute__((address_space(1))) void*)(bp1 + (K0)), (__attribute__((address_space(3))) void*)bl1, 16, 0, 0); \
    } while (0)

    int lq = l & 15, lg = l >> 4;
    STAGE(0);

    for (int k0 = 0; k0 < K; k0 += 32) {
        __syncthreads();
        short8 af[4], bfv[4];
        #pragma unroll
        for (int mi = 0; mi < 4; ++mi) {
            int r = wm + mi*16 + lq;
            int ks = lg ^ ((r >> 1) & 3);
            af[mi] = *(const short8*)&As[r*32 + ks*8];
        }
        #pragma unroll
        for (int ni = 0; ni < 4; ++ni) {
            int r = wn + ni*16 + lq;
            int ks = lg ^ ((r >> 1) & 3);
            bfv[ni] = *(const short8*)&Bs[r*32 + ks*8];
        }
        #pragma unroll
        for (int mi = 0; mi < 4; ++mi)
            #pragma unroll
            for (int ni = 0; ni < 4; ++ni)
                acc[mi][ni] = __builtin_amdgcn_mfma_f32_16x16x32_bf16(af[mi], bfv[ni], acc[mi][ni], 0, 0, 0);
        __syncthreads();
        if (k0 + 32 < K) STAGE(k0 + 32);
    }
    #undef STAGE

    // epilogue: C/D map col=lane&15, row=(lane>>4)*4+q
    int lr = (l >> 4) * 4;
    #pragma unroll
    for (int mi = 0; mi < 4; ++mi) {
        #pragma unroll
        for (int ni = 0; ni < 4; ++ni) {
            int col = bn + wn + ni*16 + lq;
            int row = bm + wm + mi*16 + lr;
            if (EPI == 4) {
                if (col < 1536) {
                    #pragma unroll
                    for (int q = 0; q < 4; ++q)
                        ((ushort*)Cout)[(size_t)(row+q)*1536 + col] = f2bf(acc[mi][ni][q]);
                } else {
                    int bb = row >> 10, t0 = row & 1023;
                    ushort4 pv = make_ushort4(f2bf(acc[mi][ni][0]), f2bf(acc[mi][ni][1]),
                                              f2bf(acc[mi][ni][2]), f2bf(acc[mi][ni][3]));
                    *(ushort4*)&((ushort*)aux)[((size_t)(bb*768) + (col-1536))*1024 + t0] = pv;
                }
            } else {
                #pragma unroll
                for (int q = 0; q < 4; ++q) {
                    size_t o = (size_t)(row + q)*N + col;
                    float v = acc[mi][ni][q];
                    if (EPI == 0) {
                        ((float*)Cout)[o] = v;
                    } else if (EPI == 1) {
                        ((float*)Cout)[o] = v + res[o];
                    } else if (EPI == 2) {
                        float t = v + bias[col];
                        ((ushort*)Cout)[o] = f2bf(0.5f*t*(1.0f + erff(t*0.70710678118f)));
                    } else {
                        ((float*)Cout)[o] = v + bias[col] + res[o];
                    }
                }
            }
        }
    }
}

// ---------------------------------------------------------------
// f32 GEMM (kept for lm_head)  C = A[M,K] @ B^T (B as [N,K])
// ---------------------------------------------------------------
template<int EPI, bool BT>
__global__ __launch_bounds__(256) void gemm_kernel(
    const float* __restrict__ A, const float* __restrict__ Bm,
    const float* __restrict__ bias, const float* __restrict__ res,
    float* __restrict__ C, int M, int N, int K)
{
    __shared__ float As[16][68];
    __shared__ float Bs[16][68];
    int tid = threadIdx.x;
    int tx = tid & 15, ty = tid >> 4;
    int bn = blockIdx.x * 64, bm = blockIdx.y * 64;
    float acc[4][4] = {};

    int arow = tid >> 2;
    int akc  = (tid & 3) * 4;
    int kb   = tid >> 4;
    int nb   = (tid & 15) * 4;

    for (int k0 = 0; k0 < K; k0 += 16) {
        float4 av = *(const float4*)&A[(size_t)(bm+arow)*K + k0 + akc];
        As[akc+0][arow] = av.x; As[akc+1][arow] = av.y;
        As[akc+2][arow] = av.z; As[akc+3][arow] = av.w;
        if (!BT) {
            float4 bv = *(const float4*)&Bm[(size_t)(k0+kb)*N + bn + nb];
            *(float4*)&Bs[kb][nb] = bv;
        } else {
            float4 bv = *(const float4*)&Bm[(size_t)(bn+arow)*K + k0 + akc];
            Bs[akc+0][arow] = bv.x; Bs[akc+1][arow] = bv.y;
            Bs[akc+2][arow] = bv.z; Bs[akc+3][arow] = bv.w;
        }
        __syncthreads();
        #pragma unroll
        for (int kk = 0; kk < 16; ++kk) {
            float4 a = *(const float4*)&As[kk][ty*4];
            float4 b = *(const float4*)&Bs[kk][tx*4];
            acc[0][0] += a.x*b.x; acc[0][1] += a.x*b.y; acc[0][2] += a.x*b.z; acc[0][3] += a.x*b.w;
            acc[1][0] += a.y*b.x; acc[1][1] += a.y*b.y; acc[1][2] += a.y*b.z; acc[1][3] += a.y*b.w;
            acc[2][0] += a.z*b.x; acc[2][1] += a.z*b.y; acc[2][2] += a.z*b.z; acc[2][3] += a.z*b.w;
            acc[3][0] += a.w*b.x; acc[3][1] += a.w*b.y; acc[3][2] += a.w*b.z; acc[3][3] += a.w*b.w;
        }
        __syncthreads();
    }

    int row0 = bm + ty*4, col0 = bn + tx*4;
    #pragma unroll
    for (int mm = 0; mm < 4; ++mm) {
        int r = row0 + mm;
        float4 vv = make_float4(acc[mm][0], acc[mm][1], acc[mm][2], acc[mm][3]);
        if (EPI == 1) {
            float4 rr = *(const float4*)&res[(size_t)r*N + col0];
            vv.x += rr.x; vv.y += rr.y; vv.z += rr.z; vv.w += rr.w;
        }
        *(float4*)&C[(size_t)r*N + col0] = vv;
    }
}

// ---------------------------------------------------------------
// MFMA flash attention.
// block = 64 q-rows of one (b,h); 4 waves; KV-tile 64.
// LDS tiles [64][64] bf16, 16B-slot XOR swizzle (slot ^= row&7).
// wave w owns q-rows w*16..+15; lane l: lq=l&15, lg=l>>4.
// QK^T: A=Q rows, B=K rows. PV: A=P rows, B=V^T rows (vt staged global).
// scores C/D map: row = w16 + lg*4 + q, col = n*16 + lq.
// ---------------------------------------------------------------
__device__ __forceinline__ int swz64(int r, int c) {
    return (r << 6) + ((((c >> 3) ^ (r & 7))) << 3) + (c & 7);
}

__device__ __forceinline__ void stage64(const ushort* __restrict__ g, int gstride,
                                        ushort* lds, int tid) {
    #pragma unroll
    for (int it = 0; it < 2; ++it) {
        int s = tid + it*256;
        int r = s >> 3, cs = (s & 7) << 3;
        short8 v = *(const short8*)&g[(size_t)r*gstride + cs];
        *(short8*)&lds[swz64(r, cs)] = v;
    }
}

__global__ __launch_bounds__(256) void attn_mfma_kernel(
    const ushort* __restrict__ qkb, const ushort* __restrict__ vtb,
    const float* __restrict__ sp,
    ushort* __restrict__ obuf, float* __restrict__ de_acc, float* __restrict__ fe_acc)
{
    __shared__ ushort Qs[64*64];
    __shared__ ushort Ks[64*64];
    __shared__ ushort Vts[64*64];
    __shared__ ushort Ps[64*64];
    __shared__ float sps[64][4];

    int tile = blockIdx.x & 15;
    int h = (blockIdx.x >> 4) % H_;
    int b = blockIdx.x / (16 * H_);
    int i0 = tile * 64;

    int tid = threadIdx.x, w = tid >> 6, l = tid & 63;
    int lq = l & 15, lg = l >> 4;
    int w16 = w * 16;

    // stage Q (visible after first loop barrier pair)
    stage64(qkb + (size_t)(b*S_ + i0)*1536 + h*64, 1536, Qs, tid);

    // per-lane q-row info
    float sq0[4], sq1[4], sq2[4];
    #pragma unroll
    for (int q = 0; q < 4; ++q) {
        int i = i0 + w16 + lg*4 + q;
        sq0[q] = sp[(b*S_+i)*3+0];
        sq1[q] = sp[(b*S_+i)*3+1];
        sq2[q] = sp[(b*S_+i)*3+2];
    }

    float M[4], Z[4], Sde[4], Sws[4];
    f32x4 O[4];
    #pragma unroll
    for (int q = 0; q < 4; ++q) { M[q] = -1e30f; Z[q] = 0.f; Sde[q] = 0.f; Sws[q] = 0.f; }
    #pragma unroll
    for (int n = 0; n < 4; ++n) { O[n][0]=0.f; O[n][1]=0.f; O[n][2]=0.f; O[n][3]=0.f; }

    const ushort* kbase = qkb + 768 + h*64;
    const ushort* vbase = vtb + (size_t)((b*H_ + h)*DH_)*S_;

    for (int j0 = 0; j0 <= i0; j0 += 64) {
        __syncthreads();   // prior tile reads complete
        stage64(kbase + (size_t)(b*S_ + j0)*1536, 1536, Ks, tid);
        stage64(vbase + j0, S_, Vts, tid);
        if (tid < 64) {
            sps[tid][0] = sp[(b*S_+j0+tid)*3+0];
            sps[tid][1] = sp[(b*S_+j0+tid)*3+1];
            sps[tid][2] = sp[(b*S_+j0+tid)*3+2];
        }
        __syncthreads();   // staging visible

        // ---- QK^T ----
        f32x4 sacc[4];
        #pragma unroll
        for (int n = 0; n < 4; ++n) { sacc[n][0]=0.f; sacc[n][1]=0.f; sacc[n][2]=0.f; sacc[n][3]=0.f; }
        short8 aq0 = *(const short8*)&Qs[swz64(w16+lq, lg*8)];
        short8 aq1 = *(const short8*)&Qs[swz64(w16+lq, 32+lg*8)];
        #pragma unroll
        for (int n = 0; n < 4; ++n) {
            short8 bk0 = *(const short8*)&Ks[swz64(n*16+lq, lg*8)];
            short8 bk1 = *(const short8*)&Ks[swz64(n*16+lq, 32+lg*8)];
            sacc[n] = __builtin_amdgcn_mfma_f32_16x16x32_bf16(aq0, bk0, sacc[n], 0, 0, 0);
            sacc[n] = __builtin_amdgcn_mfma_f32_16x16x32_bf16(aq1, bk1, sacc[n], 0, 0, 0);
        }

        // ---- penalty + mask + online softmax ----
        float dstv[4][4], ev[4][4];
        #pragma unroll
        for (int n = 0; n < 4; ++n) {
            float c0 = sps[n*16+lq][0], c1 = sps[n*16+lq][1], c2 = sps[n*16+lq][2];
            int j = j0 + n*16 + lq;
            #pragma unroll
            for (int q = 0; q < 4; ++q) {
                float e0 = sq0[q]-c0, e1 = sq1[q]-c1, e2 = sq2[q]-c2;
                float dist = sqrtf(e0*e0 + e1*e1 + e2*e2 + 1e-12f);
                dstv[n][q] = dist;
                float s = sacc[n][q]*0.125f - dist;
                sacc[n][q] = (j <= i0 + w16 + lg*4 + q) ? s : -1e30f;
            }
        }
        #pragma unroll
        for (int q = 0; q < 4; ++q) {
            float mt = fmaxf(fmaxf(sacc[0][q], sacc[1][q]), fmaxf(sacc[2][q], sacc[3][q]));
            mt = fmaxf(mt, __shfl_xor(mt, 1, 64));
            mt = fmaxf(mt, __shfl_xor(mt, 2, 64));
            mt = fmaxf(mt, __shfl_xor(mt, 4, 64));
            mt = fmaxf(mt, __shfl_xor(mt, 8, 64));
            float Mn = fmaxf(M[q], mt);
            float scale = __expf(M[q] - Mn);
            float zl = 0.f, del = 0.f, wsl = 0.f;
            #pragma unroll
            for (int n = 0; n < 4; ++n) {
                float e = __expf(sacc[n][q] - Mn);
                ev[n][q] = e;
                zl += e; del += e*dstv[n][q]; wsl += e*sacc[n][q];
            }
            zl  += __shfl_xor(zl, 1, 64);  zl  += __shfl_xor(zl, 2, 64);
            zl  += __shfl_xor(zl, 4, 64);  zl  += __shfl_xor(zl, 8, 64);
            del += __shfl_xor(del, 1, 64); del += __shfl_xor(del, 2, 64);
            del += __shfl_xor(del, 4, 64); del += __shfl_xor(del, 8, 64);
            wsl += __shfl_xor(wsl, 1, 64); wsl += __shfl_xor(wsl, 2, 64);
            wsl += __shfl_xor(wsl, 4, 64); wsl += __shfl_xor(wsl, 8, 64);
            Z[q]   = Z[q]  *scale + zl;
            Sde[q] = Sde[q]*scale + del;
            Sws[q] = Sws[q]*scale + wsl;
            M[q] = Mn;
            O[0][q] *= scale; O[1][q] *= scale; O[2][q] *= scale; O[3][q] *= scale;
        }

        // ---- P -> LDS (bf16) ----
        #pragma unroll
        for (int n = 0; n < 4; ++n)
            #pragma unroll
            for (int q = 0; q < 4; ++q)
                Ps[swz64(w16 + lg*4 + q, n*16 + lq)] = f2bf(ev[n][q]);
        __syncthreads();   // P visible (also orders intra-wave write->read)

        // ---- PV ----
        short8 pa0 = *(const short8*)&Ps[swz64(w16+lq, lg*8)];
        short8 pa1 = *(const short8*)&Ps[swz64(w16+lq, 32+lg*8)];
        #pragma unroll
        for (int n = 0; n < 4; ++n) {
            short8 v0 = *(const short8*)&Vts[swz64(n*16+lq, lg*8)];
            short8 v1 = *(const short8*)&Vts[swz64(n*16+lq, 32+lg*8)];
            O[n] = __builtin_amdgcn_mfma_f32_16x16x32_bf16(pa0, v0, O[n], 0, 0, 0);
            O[n] = __builtin_amdgcn_mfma_f32_16x16x32_bf16(pa1, v1, O[n], 0, 0, 0);
        }
    }

    // ---- epilogue ----
    #pragma unroll
    for (int q = 0; q < 4; ++q) {
        float invz = 1.0f / Z[q];
        int i = i0 + w16 + lg*4 + q;
        ushort* op = obuf + (size_t)(b*S_ + i)*D_ + h*DH_ + lq;
        op[0]  = f2bf(O[0][q]*invz);
        op[16] = f2bf(O[1][q]*invz);
        op[32] = f2bf(O[2][q]*invz);
        op[48] = f2bf(O[3][q]*invz);
    }

    float dsum = 0.f, fsum = 0.f;
    if (lq == 0) {
        #pragma unroll
        for (int q = 0; q < 4; ++q) {
            dsum += Sde[q] / Z[q];
            fsum += M[q] + __logf(Z[q]) - Sws[q] / Z[q];
        }
    }
    #pragma unroll
    for (int m = 32; m > 0; m >>= 1) {
        dsum += __shfl_xor(dsum, m, 64);
        fsum += __shfl_xor(fsum, m, 64);
    }
    if (l == 0) {
        atomicAdd(de_acc, dsum * (1.0f/49152.0f));
        atomicAdd(fe_acc, fsum * (1.0f/49152.0f));
    }
}

// ---------------------------------------------------------------
__global__ __launch_bounds__(256) void ce_kernel(
    const float* __restrict__ logits, const int* __restrict__ targets,
    float* __restrict__ ce_acc)
{
    __shared__ float red[4];
    int r = blockIdx.x, tid = threadIdx.x;
    float x = logits[(size_t)r*V_ + tid];
    float m = block_max(x, red);
    float e = __expf(x - m);
    float s = block_sum(e, red);
    if (tid == 0) {
        float lse = m + __logf(s);
        float tl = logits[(size_t)r*V_ + targets[r]];
        atomicAdd(ce_acc, (lse - tl) * (1.0f/(float)BS_));
    }
}

__global__ __launch_bounds__(256) void rep_kernel(
    const float* __restrict__ tp, float* __restrict__ rep_acc)
{
    __shared__ float red[4];
    int i = blockIdx.x, j = threadIdx.x;
    float val = 0.0f;
    if (i != j) {
        float d0 = tp[i*3+0]-tp[j*3+0];
        float d1 = tp[i*3+1]-tp[j*3+1];
        float d2 = tp[i*3+2]-tp[j*3+2];
        float dm = sqrtf(d0*d0 + d1*d1 + d2*d2 + 1e-12f);
        val = 1.0f/(dm + 1e-4f);
    }
    float s = block_sum(val, red);
    if (j == 0) atomicAdd(rep_acc, s);
}

__global__ void finalize_kernel(float* __restrict__ out4, const float* __restrict__ acc) {
    if (threadIdx.x == 0) {
        float de = acc[0], fe = acc[1];
        float rep = acc[2] * (1.0f/(256.0f*255.0f));
        float ce = acc[3];
        out4[0] = ce + 0.01f*de + 0.01f*fe + 0.01f*rep;
        out4[1] = de;
        out4[2] = fe;
        out4[3] = rep;
    }
}

// ---------------------------------------------------------------
extern "C" void kernel_launch(void* const* d_in, const int* in_sizes, int n_in,
                              void* d_out, int out_size, void* d_ws, size_t ws_size,
                              hipStream_t stream)
{
    const int*   idx      = (const int*)  d_in[0];
    const int*   targets  = (const int*)  d_in[1];
    const float* tok_emb  = (const float*)d_in[2];
    const float* pos_emb  = (const float*)d_in[3];
    const float* tok_pos  = (const float*)d_in[4];
    const float* pproj    = (const float*)d_in[5];
    const float* ln1_g    = (const float*)d_in[6];
    const float* ln1_b    = (const float*)d_in[7];
    const float* Wqkv     = (const float*)d_in[8];
    const float* Wproj    = (const float*)d_in[9];
    const float* ln2_g    = (const float*)d_in[10];
    const float* ln2_b    = (const float*)d_in[11];
    const float* Wff1     = (const float*)d_in[12];
    const float* bff1     = (const float*)d_in[13];
    const float* Wff2     = (const float*)d_in[14];
    const float* bff2     = (const float*)d_in[15];
    const float* lnf_g    = (const float*)d_in[16];
    const float* lnf_b    = (const float*)d_in[17];

    float* out = (float*)d_out;

    // workspace layout
    float* wsf  = (float*)d_ws;
    float* acc  = wsf;                                  // 8
    float* sp   = wsf + 8;                              // 12288
    float* x    = sp + 12288;                           // BS_*D_ f32
    float* hf   = x + (size_t)BS_*D_;                   // BS_*D_ f32 (lnf out)
    ushort* hbf  = (ushort*)(hf + (size_t)BS_*D_);      // BS_*D_ bf16
    ushort* ffbf = hbf + (size_t)BS_*D_;                // BS_*D4_ bf16
    ushort* qkb  = ffbf + (size_t)BS_*D4_;              // BS_*1536 bf16 (q,k)
    ushort* vtb  = qkb + (size_t)BS_*1536;              // 3072*1024 bf16 (v^T)
    ushort* wqT  = vtb + (size_t)3072*1024;             // D3_*D_
    ushort* wpT  = wqT + (size_t)D3_*D_;                // D_*D_
    ushort* w1T  = wpT + (size_t)D_*D_;                 // D4_*D_
    ushort* w2T  = w1T + (size_t)D4_*D_;                // D_*D4_

    zero_kernel<<<1, 64, 0, stream>>>(acc);
    embed_kernel<<<BS_, 256, 0, stream>>>(idx, tok_emb, pos_emb, tok_pos, pproj, x, sp);

    for (int l = 0; l < L_; ++l) {
        transpose_bf16_kernel<<<dim3(D3_/32, D_/32), 256, 0, stream>>>(Wqkv + (size_t)l*D_*D3_, wqT, D_, D3_);
        transpose_bf16_kernel<<<dim3(D_/32,  D_/32), 256, 0, stream>>>(Wproj + (size_t)l*D_*D_, wpT, D_, D_);
        transpose_bf16_kernel<<<dim3(D4_/32, D_/32), 256, 0, stream>>>(Wff1 + (size_t)l*D_*D4_, w1T, D_, D4_);
        transpose_bf16_kernel<<<dim3(D_/32, D4_/32), 256, 0, stream>>>(Wff2 + (size_t)l*D4_*D_, w2T, D4_, D_);

        ln_kernel<1><<<BS_, 256, 0, stream>>>(x, ln1_g + l*D_, ln1_b + l*D_, hbf);

        gemm_bf16_kernel<4><<<dim3(D3_/128, BS_/128), 256, 0, stream>>>(
            hbf, wqT, nullptr, nullptr, qkb, vtb, BS_, D3_, D_);

        attn_mfma_kernel<<<B_*H_*(S_/64), 256, 0, stream>>>(qkb, vtb, sp, hbf, &acc[0], &acc[1]);

        gemm_bf16_kernel<1><<<dim3(D_/128, BS_/128), 256, 0, stream>>>(
            hbf, wpT, nullptr, x, x, nullptr, BS_, D_, D_);

        ln_kernel<1><<<BS_, 256, 0, stream>>>(x, ln2_g + l*D_, ln2_b + l*D_, hbf);

        gemm_bf16_kernel<2><<<dim3(D4_/128, BS_/128), 256, 0, stream>>>(
            hbf, w1T, bff1 + (size_t)l*D4_, nullptr, ffbf, nullptr, BS_, D4_, D_);

        gemm_bf16_kernel<3><<<dim3(D_/128, BS_/128), 256, 0, stream>>>(
            ffbf, w2T, bff2 + (size_t)l*D_, x, x, nullptr, BS_, D_, D4_);
    }

    ln_kernel<0><<<BS_, 256, 0, stream>>>(x, lnf_g, lnf_b, hf);

    // tied lm_head in f32 for logit accuracy
    gemm_kernel<0,true><<<dim3(V_/64, BS_/64), 256, 0, stream>>>(
        hf, tok_emb, nullptr, nullptr, out, BS_, V_, D_);

    ce_kernel<<<BS_, 256, 0, stream>>>(out, targets, &acc[3]);
    rep_kernel<<<V_, 256, 0, stream>>>(tok_pos, &acc[2]);
    finalize_kernel<<<1, 64, 0, stream>>>(out + BSV_, acc);
}